// Round 1
// baseline (921.938 us; speedup 1.0000x reference)
//
#include <hip/hip_runtime.h>
#include <hip/hip_bf16.h>

// ---------------------------------------------------------------------------
// PairToSequenceTE:
//   z = LN(s_z); h = relu(z @ w1^T + b1)            (per pair, C=128)
//   [w2 matmul commutes with masked sums:]
//   g[l,c]  = sum_m mask[l,m] * h[l,m,c]
//   gr[m,c] = sum_l mask[l,m] * h[l,m,c]
//   s_s_c[l] = (g[l] @ w2^T + b2*Mc[l]) / max(Mc[l],1)   (Mc = mask row sums)
//   s_s_r[m] = (gr[m] @ w2^T + b2*Mr[m]) / max(Mr[m],1)
//   out = [s_s_c | s_s_r | s_s_in] @ wc^T + bc
// ---------------------------------------------------------------------------

typedef short bf16x8 __attribute__((ext_vector_type(8)));
typedef float f32x16 __attribute__((ext_vector_type(16)));

static __device__ __forceinline__ short f2bf(float f) {
  unsigned u = __float_as_uint(f);
  u += 0x7fffu + ((u >> 16) & 1u);          // RNE
  return (short)(u >> 16);
}
static __device__ __forceinline__ float bf2f(short s) {
  return __uint_as_float(((unsigned)(unsigned short)s) << 16);
}

// ---------------------------------------------------------------------------
// Kernel A: per-pair LN -> bf16 -> MFMA vs w1 -> relu/mask -> g/gr atomics
// grid (32,32) blocks of 256 threads; block tile = 32 l x 32 m pairs
// ---------------------------------------------------------------------------
__global__ __launch_bounds__(256, 2) void k_pair(
    const float* __restrict__ z, const float* __restrict__ pm,
    const float* __restrict__ lng, const float* __restrict__ lnb,
    const float* __restrict__ w1, const float* __restrict__ b1,
    float* __restrict__ g, float* __restrict__ gr)
{
  // As: 64 rows x (128+8) bf16  (stride 272B -> conflict-free b128 col reads)
  // red1 (aliased): 4096 floats for cross-wave gr reduction
  __shared__ __align__(16) char smemRaw[64 * 136 * 2];
  __shared__ float maskS[64];
  short* As   = (short*)smemRaw;
  float* red1 = (float*)smemRaw;

  const int tid  = threadIdx.x;
  const int lane = tid & 63;
  const int wv   = tid >> 6;
  const int rt   = wv >> 1;        // row-tile (which l of the batch pair)
  const int ch   = wv & 1;         // column half (64 of 128 outputs)
  const int ln   = lane & 31;
  const int hh   = lane >> 5;
  const int l0   = blockIdx.y * 32;
  const int m0   = blockIdx.x * 32;
  const int c8   = (tid & 15) * 8; // staging column start

  float lg[8], lb[8];
  #pragma unroll
  for (int j = 0; j < 8; ++j) { lg[j] = lng[c8 + j]; lb[j] = lnb[c8 + j]; }

  float b1v[2];
  #pragma unroll
  for (int cc = 0; cc < 2; ++cc) b1v[cc] = b1[(ch * 2 + cc) * 32 + ln];

  // w1 B-fragments resident in VGPRs: B[k][n] = w1[n][k], n = lane&31 (+tile)
  bf16x8 bF[2][8];
  #pragma unroll
  for (int cc = 0; cc < 2; ++cc) {
    const int n = (ch * 2 + cc) * 32 + ln;
    #pragma unroll
    for (int k0 = 0; k0 < 8; ++k0) {
      const float* wp = w1 + n * 128 + k0 * 16 + hh * 8;
      float4 f0 = *(const float4*)wp;
      float4 f1 = *(const float4*)(wp + 4);
      bf16x8 t;
      t[0]=f2bf(f0.x); t[1]=f2bf(f0.y); t[2]=f2bf(f0.z); t[3]=f2bf(f0.w);
      t[4]=f2bf(f1.x); t[5]=f2bf(f1.y); t[6]=f2bf(f1.z); t[7]=f2bf(f1.w);
      bF[cc][k0] = t;
    }
  }

  float grA[2][16];
  #pragma unroll
  for (int cc = 0; cc < 2; ++cc)
    #pragma unroll
    for (int i = 0; i < 16; ++i) grA[cc][i] = 0.f;

  #pragma unroll 1
  for (int b = 0; b < 16; ++b) {
    if (b) __syncthreads();
    // ---- stage 64 rows (2 l x 32 m) with fused LayerNorm ----
    float4 xa[4], xb[4];
    #pragma unroll
    for (int p = 0; p < 4; ++p) {
      const int r = p * 16 + (tid >> 4);
      const int l = l0 + b * 2 + (r >> 5);
      const int m = m0 + (r & 31);
      const float* src = z + ((size_t)l * 1024 + (size_t)m) * 128 + c8;
      xa[p] = *(const float4*)src;
      xb[p] = *(const float4*)(src + 4);
    }
    if (tid < 64) {
      const int l = l0 + b * 2 + (tid >> 5);
      maskS[tid] = pm[(size_t)l * 1024 + (m0 + (tid & 31))];
    }
    #pragma unroll
    for (int p = 0; p < 4; ++p) {
      const int r = p * 16 + (tid >> 4);
      float x[8] = {xa[p].x, xa[p].y, xa[p].z, xa[p].w,
                    xb[p].x, xb[p].y, xb[p].z, xb[p].w};
      float s = 0.f, s2 = 0.f;
      #pragma unroll
      for (int j = 0; j < 8; ++j) { s += x[j]; s2 += x[j] * x[j]; }
      #pragma unroll
      for (int off = 1; off < 16; off <<= 1) {
        s  += __shfl_xor(s, off);
        s2 += __shfl_xor(s2, off);
      }
      const float mu  = s * (1.f / 128.f);
      const float var = s2 * (1.f / 128.f) - mu * mu;
      const float rs  = rsqrtf(var + 1e-5f);
      bf16x8 o;
      #pragma unroll
      for (int j = 0; j < 8; ++j) o[j] = f2bf((x[j] - mu) * rs * lg[j] + lb[j]);
      *(bf16x8*)(As + r * 136 + c8) = o;
    }
    __syncthreads();

    // ---- MFMA: 32 rows x 64 cols per wave, K=128 ----
    f32x16 acc0, acc1;
    #pragma unroll
    for (int i = 0; i < 16; ++i) { acc0[i] = 0.f; acc1[i] = 0.f; }
    #pragma unroll
    for (int k0 = 0; k0 < 8; ++k0) {
      bf16x8 aF = *(bf16x8*)(As + (rt * 32 + ln) * 136 + k0 * 16 + hh * 8);
      acc0 = __builtin_amdgcn_mfma_f32_32x32x16_bf16(aF, bF[0][k0], acc0, 0, 0, 0);
      acc1 = __builtin_amdgcn_mfma_f32_32x32x16_bf16(aF, bF[1][k0], acc1, 0, 0, 0);
    }

    // ---- epilogue: bias, relu, mask; accumulate row (g) and col (gr) sums ----
    float mrow[16];
    #pragma unroll
    for (int i = 0; i < 16; ++i) {
      const int cr = (i & 3) + 8 * (i >> 2) + 4 * hh;  // C/D row (= m_local)
      mrow[i] = maskS[rt * 32 + cr];
    }
    const int lrow = l0 + b * 2 + rt;
    float s0 = 0.f, s1 = 0.f;
    #pragma unroll
    for (int i = 0; i < 16; ++i) {
      const float v0 = fmaxf(acc0[i] + b1v[0], 0.f) * mrow[i];
      const float v1 = fmaxf(acc1[i] + b1v[1], 0.f) * mrow[i];
      grA[0][i] += v0; grA[1][i] += v1;
      s0 += v0; s1 += v1;
    }
    s0 += __shfl_xor(s0, 32);
    s1 += __shfl_xor(s1, 32);
    if (lane < 32) {
      atomicAdd(&g[lrow * 128 + (ch * 2 + 0) * 32 + lane], s0);
      atomicAdd(&g[lrow * 128 + (ch * 2 + 1) * 32 + lane], s1);
    }
  }

  // ---- cross-wave reduce of gr partials (rt=1 stages, rt=0 adds+atomics) ----
  __syncthreads();
  if (rt == 1) {
    #pragma unroll
    for (int cc = 0; cc < 2; ++cc)
      #pragma unroll
      for (int i = 0; i < 16; ++i) {
        const int cr = (i & 3) + 8 * (i >> 2) + 4 * hh;
        red1[((ch * 2 + cc) * 32 + cr) * 32 + ln] = grA[cc][i];
      }
  }
  __syncthreads();
  if (rt == 0) {
    #pragma unroll
    for (int cc = 0; cc < 2; ++cc)
      #pragma unroll
      for (int i = 0; i < 16; ++i) {
        const int cr = (i & 3) + 8 * (i >> 2) + 4 * hh;
        const float v = grA[cc][i] + red1[((ch * 2 + cc) * 32 + cr) * 32 + ln];
        atomicAdd(&gr[(m0 + cr) * 128 + (ch * 2 + cc) * 32 + ln], v);
      }
  }
}

// ---------------------------------------------------------------------------
// Kernel B: mask row/col sums. grid 4 x 256 (1024 threads total)
// ---------------------------------------------------------------------------
__global__ void k_masksum(const float* __restrict__ pm,
                          float* __restrict__ Mc, float* __restrict__ Mr)
{
  const int t = blockIdx.x * 256 + threadIdx.x;  // 0..1023
  float s = 0.f;
  for (int l = 0; l < 1024; ++l) s += pm[(size_t)l * 1024 + t];
  Mr[t] = s;

  const int w = t >> 6, lane = t & 63;           // 16 waves total
  for (int l = w; l < 1024; l += 16) {
    float v = 0.f;
    #pragma unroll 4
    for (int i = 0; i < 16; ++i) v += pm[(size_t)l * 1024 + i * 64 + lane];
    #pragma unroll
    for (int off = 1; off < 64; off <<= 1) v += __shfl_xor(v, off);
    if (lane == 0) Mc[l] = v;
  }
}

// ---------------------------------------------------------------------------
// Kernel C: ss[p] = (gg[p] @ w2^T + b2*M[p]) / max(M[p],1), p in [0,2048)
// (rows 0..1023 = g -> s_s_c ; rows 1024..2047 = gr -> s_s_r). grid 32 x 256.
// ---------------------------------------------------------------------------
__global__ __launch_bounds__(256, 2) void k_seqproj(
    const float* __restrict__ gg, const float* __restrict__ w2,
    const float* __restrict__ b2, const float* __restrict__ Mc,
    const float* __restrict__ Mr, float* __restrict__ ss)
{
  __shared__ __align__(16) char smemRaw[64 * 136 * 2];
  __shared__ float Mvs[64];
  short* As = (short*)smemRaw;

  const int tid = threadIdx.x, lane = tid & 63, wv = tid >> 6;
  const int rt = wv >> 1, ch = wv & 1, ln = lane & 31, hh = lane >> 5;
  const int r0 = blockIdx.x * 64;
  const int c8 = (tid & 15) * 8;

  float b2v[2];
  #pragma unroll
  for (int cc = 0; cc < 2; ++cc) b2v[cc] = b2[(ch * 2 + cc) * 32 + ln];

  bf16x8 bF[2][8];
  #pragma unroll
  for (int cc = 0; cc < 2; ++cc) {
    const int n = (ch * 2 + cc) * 32 + ln;
    #pragma unroll
    for (int k0 = 0; k0 < 8; ++k0) {
      const float* wp = w2 + n * 128 + k0 * 16 + hh * 8;
      float4 f0 = *(const float4*)wp;
      float4 f1 = *(const float4*)(wp + 4);
      bf16x8 t;
      t[0]=f2bf(f0.x); t[1]=f2bf(f0.y); t[2]=f2bf(f0.z); t[3]=f2bf(f0.w);
      t[4]=f2bf(f1.x); t[5]=f2bf(f1.y); t[6]=f2bf(f1.z); t[7]=f2bf(f1.w);
      bF[cc][k0] = t;
    }
  }

  #pragma unroll
  for (int p = 0; p < 4; ++p) {
    const int r = p * 16 + (tid >> 4);
    const float* src = gg + (size_t)(r0 + r) * 128 + c8;
    float4 f0 = *(const float4*)src;
    float4 f1 = *(const float4*)(src + 4);
    bf16x8 o;
    o[0]=f2bf(f0.x); o[1]=f2bf(f0.y); o[2]=f2bf(f0.z); o[3]=f2bf(f0.w);
    o[4]=f2bf(f1.x); o[5]=f2bf(f1.y); o[6]=f2bf(f1.z); o[7]=f2bf(f1.w);
    *(bf16x8*)(As + r * 136 + c8) = o;
  }
  if (tid < 64) {
    const int p = r0 + tid;
    Mvs[tid] = (p < 1024) ? Mc[p] : Mr[p - 1024];
  }
  __syncthreads();

  f32x16 acc0, acc1;
  #pragma unroll
  for (int i = 0; i < 16; ++i) { acc0[i] = 0.f; acc1[i] = 0.f; }
  #pragma unroll
  for (int k0 = 0; k0 < 8; ++k0) {
    bf16x8 aF = *(bf16x8*)(As + (rt * 32 + ln) * 136 + k0 * 16 + hh * 8);
    acc0 = __builtin_amdgcn_mfma_f32_32x32x16_bf16(aF, bF[0][k0], acc0, 0, 0, 0);
    acc1 = __builtin_amdgcn_mfma_f32_32x32x16_bf16(aF, bF[1][k0], acc1, 0, 0, 0);
  }

  #pragma unroll
  for (int i = 0; i < 16; ++i) {
    const int cr = (i & 3) + 8 * (i >> 2) + 4 * hh;
    const int p = r0 + rt * 32 + cr;
    const float mv = Mvs[rt * 32 + cr];
    const float dn = fmaxf(mv, 1.f);
    ss[(size_t)p * 128 + (ch * 2 + 0) * 32 + ln] = (acc0[i] + b2v[0] * mv) / dn;
    ss[(size_t)p * 128 + (ch * 2 + 1) * 32 + ln] = (acc1[i] + b2v[1] * mv) / dn;
  }
}

// ---------------------------------------------------------------------------
// Kernel D: out = [s_s_c|s_s_r|s_s_in] @ wc^T + bc, split-bf16 (hi/lo) MFMA:
// acc += Ah*Bh + Ah*Bl + Al*Bh  (~fp32 quality). Tile 64x64, BK=32.
// grid (16,16) x 256.
// ---------------------------------------------------------------------------
__global__ __launch_bounds__(256, 2) void k_final(
    const float* __restrict__ ss, const float* __restrict__ s_in,
    const float* __restrict__ wc, const float* __restrict__ bc,
    float* __restrict__ out)
{
  __shared__ __align__(16) short Ah[64 * 40], Al[64 * 40];
  __shared__ __align__(16) short Bh[64 * 40], Bl[64 * 40];
  const int tid = threadIdx.x, lane = tid & 63, wv = tid >> 6;
  const int mi = (wv >> 1) * 32, ni = (wv & 1) * 32;
  const int ln = lane & 31, hh = lane >> 5;
  const int m0 = blockIdx.y * 64, n0 = blockIdx.x * 64;
  const int rS = tid >> 2;        // staging row 0..63
  const int kb = (tid & 3) * 8;   // staging col 0,8,16,24

  const float bcv = bc[n0 + ni + ln];
  f32x16 acc;
  #pragma unroll
  for (int i = 0; i < 16; ++i) acc[i] = 0.f;

  #pragma unroll 1
  for (int kk0 = 0; kk0 < 1280; kk0 += 32) {
    if (kk0) __syncthreads();
    // A source select (uniform per chunk: region boundaries are 32-aligned)
    const float* srcA;
    if (kk0 < 128)      srcA = ss + (size_t)(m0 + rS) * 128 + kk0 + kb;
    else if (kk0 < 256) srcA = ss + (size_t)(1024 + m0 + rS) * 128 + (kk0 - 128) + kb;
    else                srcA = s_in + (size_t)(m0 + rS) * 1024 + (kk0 - 256) + kb;
    float4 a0 = *(const float4*)srcA;
    float4 a1 = *(const float4*)(srcA + 4);
    const float* srcB = wc + (size_t)(n0 + rS) * 1280 + kk0 + kb;
    float4 b0 = *(const float4*)srcB;
    float4 b1_ = *(const float4*)(srcB + 4);

    float av[8] = {a0.x,a0.y,a0.z,a0.w,a1.x,a1.y,a1.z,a1.w};
    float bv[8] = {b0.x,b0.y,b0.z,b0.w,b1_.x,b1_.y,b1_.z,b1_.w};
    bf16x8 vah, val_, vbh, vbl;
    #pragma unroll
    for (int j = 0; j < 8; ++j) {
      const short ha = f2bf(av[j]);
      vah[j] = ha; val_[j] = f2bf(av[j] - bf2f(ha));
      const short hb = f2bf(bv[j]);
      vbh[j] = hb; vbl[j] = f2bf(bv[j] - bf2f(hb));
    }
    *(bf16x8*)(Ah + rS * 40 + kb) = vah;
    *(bf16x8*)(Al + rS * 40 + kb) = val_;
    *(bf16x8*)(Bh + rS * 40 + kb) = vbh;
    *(bf16x8*)(Bl + rS * 40 + kb) = vbl;
    __syncthreads();

    #pragma unroll
    for (int k0 = 0; k0 < 2; ++k0) {
      bf16x8 aH = *(bf16x8*)(Ah + (mi + ln) * 40 + k0 * 16 + hh * 8);
      bf16x8 aL = *(bf16x8*)(Al + (mi + ln) * 40 + k0 * 16 + hh * 8);
      bf16x8 bH = *(bf16x8*)(Bh + (ni + ln) * 40 + k0 * 16 + hh * 8);
      bf16x8 bL = *(bf16x8*)(Bl + (ni + ln) * 40 + k0 * 16 + hh * 8);
      acc = __builtin_amdgcn_mfma_f32_32x32x16_bf16(aH, bH, acc, 0, 0, 0);
      acc = __builtin_amdgcn_mfma_f32_32x32x16_bf16(aH, bL, acc, 0, 0, 0);
      acc = __builtin_amdgcn_mfma_f32_32x32x16_bf16(aL, bH, acc, 0, 0, 0);
    }
  }

  #pragma unroll
  for (int i = 0; i < 16; ++i) {
    const int cr = (i & 3) + 8 * (i >> 2) + 4 * hh;
    out[(size_t)(m0 + mi + cr) * 1024 + n0 + ni + ln] = acc[i] + bcv;
  }
}

// ---------------------------------------------------------------------------
extern "C" void kernel_launch(void* const* d_in, const int* in_sizes, int n_in,
                              void* d_out, int out_size, void* d_ws, size_t ws_size,
                              hipStream_t stream) {
  const float* s_z    = (const float*)d_in[0];
  const float* s_s_in = (const float*)d_in[1];
  const float* pmask  = (const float*)d_in[2];
  const float* ln_g   = (const float*)d_in[3];
  const float* ln_b   = (const float*)d_in[4];
  const float* w1     = (const float*)d_in[5];
  const float* b1     = (const float*)d_in[6];
  const float* w2     = (const float*)d_in[7];
  const float* b2     = (const float*)d_in[8];
  const float* wc     = (const float*)d_in[9];
  const float* bc     = (const float*)d_in[10];
  float* outp = (float*)d_out;

  // workspace layout (floats): g[1024*128] | gr[1024*128] | Mc[1024] | Mr[1024] | ss[2048*128]
  float* g  = (float*)d_ws;
  float* gr = g  + 1024 * 128;
  float* Mc = gr + 1024 * 128;
  float* Mr = Mc + 1024;
  float* ss = Mr + 1024;

  hipMemsetAsync(d_ws, 0, (size_t)2 * 1024 * 128 * sizeof(float), stream);

  k_pair<<<dim3(32, 32), 256, 0, stream>>>(s_z, pmask, ln_g, ln_b, w1, b1, g, gr);
  k_masksum<<<4, 256, 0, stream>>>(pmask, Mc, Mr);
  k_seqproj<<<32, 256, 0, stream>>>(g, w2, b2, Mc, Mr, ss);
  k_final<<<dim3(16, 16), 256, 0, stream>>>(ss, s_s_in, wc, bc, outp);
}

// Round 2
// 764.168 us; speedup vs baseline: 1.2065x; 1.2065x over previous
//
#include <hip/hip_runtime.h>
#include <hip/hip_bf16.h>

// ---------------------------------------------------------------------------
// PairToSequenceTE:
//   z = LN(s_z); h = relu(z @ w1^T + b1)            (per pair, C=128)
//   [w2 matmul commutes with masked sums:]
//   g[l,c]  = sum_m mask[l,m] * h[l,m,c]
//   gr[m,c] = sum_l mask[l,m] * h[l,m,c]
//   s_s_c[l] = (g[l] @ w2^T + b2*Mc[l]) / max(Mc[l],1)
//   s_s_r[m] = (gr[m] @ w2^T + b2*Mr[m]) / max(Mr[m],1)
//   out = [s_s_c | s_s_r | s_s_in] @ wc^T + bc   (split-bf16 3-product MFMA)
// ---------------------------------------------------------------------------

typedef short bf16x8 __attribute__((ext_vector_type(8)));
typedef short short4v __attribute__((ext_vector_type(4)));
typedef float f32x16 __attribute__((ext_vector_type(16)));

static __device__ __forceinline__ short f2bf(float f) {
  unsigned u = __float_as_uint(f);
  u += 0x7fffu + ((u >> 16) & 1u);          // RNE
  return (short)(u >> 16);
}
static __device__ __forceinline__ float bf2f(short s) {
  return __uint_as_float(((unsigned)(unsigned short)s) << 16);
}

// ---------------------------------------------------------------------------
// Kernel A: per-pair LN -> bf16 -> MFMA vs w1 -> relu/mask -> g/gr atomics.
// Double-buffered LDS + register prefetch: one barrier per batch, next batch's
// global loads overlap current batch's MFMA+epilogue. Also folds mask row/col
// sums (Mc/Mr) into wave 0 (mask tile is already resident).
// grid (32,32) x 256; block tile = 32 l x 32 m pairs; 16 batches of 2 l-rows.
// ---------------------------------------------------------------------------
__global__ __launch_bounds__(256, 2) void k_pair(
    const float* __restrict__ z, const float* __restrict__ pm,
    const float* __restrict__ lng, const float* __restrict__ lnb,
    const float* __restrict__ w1, const float* __restrict__ b1,
    float* __restrict__ g, float* __restrict__ gr,
    float* __restrict__ Mc, float* __restrict__ Mr)
{
  // As: 2 x (64 rows x 136 shorts); stride 272B (16B-aligned rows for b128)
  __shared__ __align__(16) short As[2][64 * 136];
  __shared__ float maskS[2][64];

  const int tid  = threadIdx.x;
  const int lane = tid & 63;
  const int wv   = tid >> 6;
  const int rt   = wv >> 1;        // which l of the batch pair
  const int ch   = wv & 1;         // column half (64 of 128 outputs)
  const int ln   = lane & 31;
  const int hh   = lane >> 5;
  const int l0   = blockIdx.y * 32;
  const int m0   = blockIdx.x * 32;
  const int c8   = (tid & 15) * 8; // staging column start

  float lg[8], lb[8];
  #pragma unroll
  for (int j = 0; j < 8; ++j) { lg[j] = lng[c8 + j]; lb[j] = lnb[c8 + j]; }

  float b1v[2];
  #pragma unroll
  for (int cc = 0; cc < 2; ++cc) b1v[cc] = b1[(ch * 2 + cc) * 32 + ln];

  // w1 B-fragments resident in VGPRs: B[k][n] = w1[n][k]
  bf16x8 bF[2][8];
  #pragma unroll
  for (int cc = 0; cc < 2; ++cc) {
    const int n = (ch * 2 + cc) * 32 + ln;
    #pragma unroll
    for (int k0 = 0; k0 < 8; ++k0) {
      const float* wp = w1 + n * 128 + k0 * 16 + hh * 8;
      float4 f0 = *(const float4*)wp;
      float4 f1 = *(const float4*)(wp + 4);
      bf16x8 t;
      t[0]=f2bf(f0.x); t[1]=f2bf(f0.y); t[2]=f2bf(f0.z); t[3]=f2bf(f0.w);
      t[4]=f2bf(f1.x); t[5]=f2bf(f1.y); t[6]=f2bf(f1.z); t[7]=f2bf(f1.w);
      bF[cc][k0] = t;
    }
  }

  float grA[2][16];
  #pragma unroll
  for (int cc = 0; cc < 2; ++cc)
    #pragma unroll
    for (int i = 0; i < 16; ++i) grA[cc][i] = 0.f;
  float mrAcc = 0.f;

  float4 xa[4], xb[4];
  float  mv = 0.f;
  auto LOADB = [&](int b) {
    #pragma unroll
    for (int p = 0; p < 4; ++p) {
      const int r = p * 16 + (tid >> 4);
      const int l = l0 + b * 2 + (r >> 5);
      const int m = m0 + (r & 31);
      const float* src = z + ((size_t)l * 1024 + (size_t)m) * 128 + c8;
      xa[p] = *(const float4*)src;
      xb[p] = *(const float4*)(src + 4);
    }
    if (tid < 64)
      mv = pm[(size_t)(l0 + b * 2 + (tid >> 5)) * 1024 + (m0 + (tid & 31))];
  };

  LOADB(0);

  #pragma unroll 1
  for (int b = 0; b < 16; ++b) {
    const int buf = b & 1;
    // ---- LayerNorm on prefetched regs, write LDS buf ----
    #pragma unroll
    for (int p = 0; p < 4; ++p) {
      const int r = p * 16 + (tid >> 4);
      float x[8] = {xa[p].x, xa[p].y, xa[p].z, xa[p].w,
                    xb[p].x, xb[p].y, xb[p].z, xb[p].w};
      float s = 0.f, s2 = 0.f;
      #pragma unroll
      for (int j = 0; j < 8; ++j) { s += x[j]; s2 += x[j] * x[j]; }
      #pragma unroll
      for (int off = 1; off < 16; off <<= 1) {
        s  += __shfl_xor(s, off);
        s2 += __shfl_xor(s2, off);
      }
      const float mu  = s * (1.f / 128.f);
      const float var = s2 * (1.f / 128.f) - mu * mu;
      const float rs  = rsqrtf(var + 1e-5f);
      bf16x8 o;
      #pragma unroll
      for (int j = 0; j < 8; ++j) o[j] = f2bf((x[j] - mu) * rs * lg[j] + lb[j]);
      *(bf16x8*)(&As[buf][r * 136 + c8]) = o;
    }
    if (tid < 64) maskS[buf][tid] = mv;
    __syncthreads();

    // ---- prefetch next batch (overlaps MFMA + epilogue below) ----
    if (b < 15) LOADB(b + 1);

    // ---- MFMA: 32 rows x 64 cols per wave, K=128 ----
    f32x16 acc0, acc1;
    #pragma unroll
    for (int i = 0; i < 16; ++i) { acc0[i] = 0.f; acc1[i] = 0.f; }
    #pragma unroll
    for (int k0 = 0; k0 < 8; ++k0) {
      bf16x8 aF = *(bf16x8*)(&As[buf][(rt * 32 + ln) * 136 + k0 * 16 + hh * 8]);
      acc0 = __builtin_amdgcn_mfma_f32_32x32x16_bf16(aF, bF[0][k0], acc0, 0, 0, 0);
      acc1 = __builtin_amdgcn_mfma_f32_32x32x16_bf16(aF, bF[1][k0], acc1, 0, 0, 0);
    }

    // ---- epilogue: bias, relu, mask; g atomics + gr register accum ----
    float mrow[16];
    #pragma unroll
    for (int i = 0; i < 16; ++i) {
      const int cr = (i & 3) + 8 * (i >> 2) + 4 * hh;  // C/D row (= m_local)
      mrow[i] = maskS[buf][rt * 32 + cr];
    }
    const int lrow = l0 + b * 2 + rt;
    float s0 = 0.f, s1 = 0.f;
    #pragma unroll
    for (int i = 0; i < 16; ++i) {
      const float v0 = fmaxf(acc0[i] + b1v[0], 0.f) * mrow[i];
      const float v1 = fmaxf(acc1[i] + b1v[1], 0.f) * mrow[i];
      grA[0][i] += v0; grA[1][i] += v1;
      s0 += v0; s1 += v1;
    }
    s0 += __shfl_xor(s0, 32);
    s1 += __shfl_xor(s1, 32);
    if (lane < 32) {
      atomicAdd(&g[lrow * 128 + (ch * 2 + 0) * 32 + lane], s0);
      atomicAdd(&g[lrow * 128 + (ch * 2 + 1) * 32 + lane], s1);
    }

    // ---- wave 0: mask row sums (Mc) + column accum (Mr) ----
    if (wv == 0) {
      const float v = maskS[buf][lane];
      mrAcc += v;
      float rsum = v;
      #pragma unroll
      for (int off = 1; off < 32; off <<= 1) rsum += __shfl_xor(rsum, off);
      if (ln == 0) atomicAdd(&Mc[l0 + b * 2 + hh], rsum);
    }
  }

  if (wv == 0) {
    const float v = mrAcc + __shfl_xor(mrAcc, 32);
    if (lane < 32) atomicAdd(&Mr[m0 + lane], v);
  }

  // ---- cross-wave reduce of gr partials (rt=1 stages, rt=0 adds+atomics) ----
  __syncthreads();
  float* red1 = (float*)&As[0][0];   // 4096 floats scratch
  if (rt == 1) {
    #pragma unroll
    for (int cc = 0; cc < 2; ++cc)
      #pragma unroll
      for (int i = 0; i < 16; ++i) {
        const int cr = (i & 3) + 8 * (i >> 2) + 4 * hh;
        red1[((ch * 2 + cc) * 32 + cr) * 32 + ln] = grA[cc][i];
      }
  }
  __syncthreads();
  if (rt == 0) {
    #pragma unroll
    for (int cc = 0; cc < 2; ++cc)
      #pragma unroll
      for (int i = 0; i < 16; ++i) {
        const int cr = (i & 3) + 8 * (i >> 2) + 4 * hh;
        const float v = grA[cc][i] + red1[((ch * 2 + cc) * 32 + cr) * 32 + ln];
        atomicAdd(&gr[(m0 + cr) * 128 + (ch * 2 + cc) * 32 + ln], v);
      }
  }
}

// ---------------------------------------------------------------------------
// Kernel C: rows p of [g;gr] -> (p @ w2^T + b2*M)/max(M,1), written directly
// as split hi/lo bf16 into the concatenated A matrix for k_final.
// p<1024 -> A[p, 0:128]; p>=1024 -> A[p-1024, 128:256]. grid 32 x 256.
// ---------------------------------------------------------------------------
__global__ __launch_bounds__(256, 2) void k_seqproj(
    const float* __restrict__ gg, const float* __restrict__ w2,
    const float* __restrict__ b2, const float* __restrict__ Mc,
    const float* __restrict__ Mr, short* __restrict__ Ah, short* __restrict__ Al)
{
  __shared__ __align__(16) short As[64 * 136];
  __shared__ float Mvs[64];

  const int tid = threadIdx.x, lane = tid & 63, wv = tid >> 6;
  const int rt = wv >> 1, ch = wv & 1, ln = lane & 31, hh = lane >> 5;
  const int r0 = blockIdx.x * 64;
  const int c8 = (tid & 15) * 8;

  float b2v[2];
  #pragma unroll
  for (int cc = 0; cc < 2; ++cc) b2v[cc] = b2[(ch * 2 + cc) * 32 + ln];

  bf16x8 bF[2][8];
  #pragma unroll
  for (int cc = 0; cc < 2; ++cc) {
    const int n = (ch * 2 + cc) * 32 + ln;
    #pragma unroll
    for (int k0 = 0; k0 < 8; ++k0) {
      const float* wp = w2 + n * 128 + k0 * 16 + hh * 8;
      float4 f0 = *(const float4*)wp;
      float4 f1 = *(const float4*)(wp + 4);
      bf16x8 t;
      t[0]=f2bf(f0.x); t[1]=f2bf(f0.y); t[2]=f2bf(f0.z); t[3]=f2bf(f0.w);
      t[4]=f2bf(f1.x); t[5]=f2bf(f1.y); t[6]=f2bf(f1.z); t[7]=f2bf(f1.w);
      bF[cc][k0] = t;
    }
  }

  #pragma unroll
  for (int p = 0; p < 4; ++p) {
    const int r = p * 16 + (tid >> 4);
    const float* src = gg + (size_t)(r0 + r) * 128 + c8;
    float4 f0 = *(const float4*)src;
    float4 f1 = *(const float4*)(src + 4);
    bf16x8 o;
    o[0]=f2bf(f0.x); o[1]=f2bf(f0.y); o[2]=f2bf(f0.z); o[3]=f2bf(f0.w);
    o[4]=f2bf(f1.x); o[5]=f2bf(f1.y); o[6]=f2bf(f1.z); o[7]=f2bf(f1.w);
    *(bf16x8*)(&As[r * 136 + c8]) = o;
  }
  if (tid < 64) {
    const int p = r0 + tid;
    Mvs[tid] = (p < 1024) ? Mc[p] : Mr[p - 1024];
  }
  __syncthreads();

  f32x16 acc0, acc1;
  #pragma unroll
  for (int i = 0; i < 16; ++i) { acc0[i] = 0.f; acc1[i] = 0.f; }
  #pragma unroll
  for (int k0 = 0; k0 < 8; ++k0) {
    bf16x8 aF = *(bf16x8*)(&As[(rt * 32 + ln) * 136 + k0 * 16 + hh * 8]);
    acc0 = __builtin_amdgcn_mfma_f32_32x32x16_bf16(aF, bF[0][k0], acc0, 0, 0, 0);
    acc1 = __builtin_amdgcn_mfma_f32_32x32x16_bf16(aF, bF[1][k0], acc1, 0, 0, 0);
  }

  const int base = (r0 < 1024) ? 0 : 128;   // uniform per block
  #pragma unroll
  for (int i = 0; i < 16; ++i) {
    const int cr = (i & 3) + 8 * (i >> 2) + 4 * hh;
    const int p = r0 + rt * 32 + cr;
    const int row = p & 1023;
    const float mvv = Mvs[rt * 32 + cr];
    const float dn = fmaxf(mvv, 1.f);
    const float v0 = (acc0[i] + b2v[0] * mvv) / dn;
    const float v1 = (acc1[i] + b2v[1] * mvv) / dn;
    const int c0 = base + (ch * 2 + 0) * 32 + ln;
    const int c1 = base + (ch * 2 + 1) * 32 + ln;
    const short h0 = f2bf(v0), h1 = f2bf(v1);
    Ah[(size_t)row * 1280 + c0] = h0;
    Al[(size_t)row * 1280 + c0] = f2bf(v0 - bf2f(h0));
    Ah[(size_t)row * 1280 + c1] = h1;
    Al[(size_t)row * 1280 + c1] = f2bf(v1 - bf2f(h1));
  }
}

// ---------------------------------------------------------------------------
// Kernel S: one-time hi/lo bf16 split of s_in -> A[:,256:1280] and wc -> B.
// grid 1280 x 256; each thread handles one float4 of each region.
// ---------------------------------------------------------------------------
__global__ void k_split(const float* __restrict__ s_in, const float* __restrict__ wc,
                        short* __restrict__ Ah, short* __restrict__ Al,
                        short* __restrict__ Bh, short* __restrict__ Bl)
{
  const int idx = blockIdx.x * 256 + threadIdx.x;

  if (idx < 262144) {                      // s_in: 1024 x 1024
    const int row = idx >> 8;
    const int c4  = (idx & 255) * 4;
    float4 v = *(const float4*)(s_in + (size_t)row * 1024 + c4);
    float x[4] = {v.x, v.y, v.z, v.w};
    short4v hi, lo;
    #pragma unroll
    for (int j = 0; j < 4; ++j) {
      const short h = f2bf(x[j]);
      hi[j] = h; lo[j] = f2bf(x[j] - bf2f(h));
    }
    const size_t o = (size_t)row * 1280 + 256 + c4;
    *(short4v*)(Ah + o) = hi;
    *(short4v*)(Al + o) = lo;
  }
  if (idx < 327680) {                      // wc: 1024 x 1280
    const int row = idx / 320;
    const int c4  = (idx - row * 320) * 4;
    float4 v = *(const float4*)(wc + (size_t)row * 1280 + c4);
    float x[4] = {v.x, v.y, v.z, v.w};
    short4v hi, lo;
    #pragma unroll
    for (int j = 0; j < 4; ++j) {
      const short h = f2bf(x[j]);
      hi[j] = h; lo[j] = f2bf(x[j] - bf2f(h));
    }
    const size_t o = (size_t)row * 1280 + c4;
    *(short4v*)(Bh + o) = hi;
    *(short4v*)(Bl + o) = lo;
  }
}

// ---------------------------------------------------------------------------
// Kernel D: out = A @ B^T + bc with A,B preconverted hi/lo bf16 (1024x1280).
// 3-product split-bf16 MFMA (Ah*Bh + Ah*Bl + Al*Bh). Tile 64x64, BK=32,
// register prefetch. grid (16,16) x 256.
// ---------------------------------------------------------------------------
__global__ __launch_bounds__(256, 2) void k_final(
    const short* __restrict__ Ah, const short* __restrict__ Al,
    const short* __restrict__ Bh, const short* __restrict__ Bl,
    const float* __restrict__ bc, float* __restrict__ out)
{
  __shared__ __align__(16) short sAh[64 * 40], sAl[64 * 40];
  __shared__ __align__(16) short sBh[64 * 40], sBl[64 * 40];
  const int tid = threadIdx.x, lane = tid & 63, wv = tid >> 6;
  const int mi = (wv >> 1) * 32, ni = (wv & 1) * 32;
  const int ln = lane & 31, hh = lane >> 5;
  const int m0 = blockIdx.y * 64, n0 = blockIdx.x * 64;
  const int rS = tid >> 2;        // staging row 0..63
  const int kb = (tid & 3) * 8;   // staging col 0,8,16,24

  const float bcv = bc[n0 + ni + ln];
  f32x16 acc;
  #pragma unroll
  for (int i = 0; i < 16; ++i) acc[i] = 0.f;

  bf16x8 rAh, rAl, rBh, rBl;
  auto LOADK = [&](int kk0) {
    rAh = *(const bf16x8*)(Ah + (size_t)(m0 + rS) * 1280 + kk0 + kb);
    rAl = *(const bf16x8*)(Al + (size_t)(m0 + rS) * 1280 + kk0 + kb);
    rBh = *(const bf16x8*)(Bh + (size_t)(n0 + rS) * 1280 + kk0 + kb);
    rBl = *(const bf16x8*)(Bl + (size_t)(n0 + rS) * 1280 + kk0 + kb);
  };
  LOADK(0);

  #pragma unroll 1
  for (int kk0 = 0; kk0 < 1280; kk0 += 32) {
    if (kk0) __syncthreads();
    *(bf16x8*)(sAh + rS * 40 + kb) = rAh;
    *(bf16x8*)(sAl + rS * 40 + kb) = rAl;
    *(bf16x8*)(sBh + rS * 40 + kb) = rBh;
    *(bf16x8*)(sBl + rS * 40 + kb) = rBl;
    __syncthreads();
    if (kk0 < 1280 - 32) LOADK(kk0 + 32);   // overlaps MFMA below

    #pragma unroll
    for (int k0 = 0; k0 < 2; ++k0) {
      bf16x8 aH = *(bf16x8*)(sAh + (mi + ln) * 40 + k0 * 16 + hh * 8);
      bf16x8 aL = *(bf16x8*)(sAl + (mi + ln) * 40 + k0 * 16 + hh * 8);
      bf16x8 bH = *(bf16x8*)(sBh + (ni + ln) * 40 + k0 * 16 + hh * 8);
      bf16x8 bL = *(bf16x8*)(sBl + (ni + ln) * 40 + k0 * 16 + hh * 8);
      acc = __builtin_amdgcn_mfma_f32_32x32x16_bf16(aH, bH, acc, 0, 0, 0);
      acc = __builtin_amdgcn_mfma_f32_32x32x16_bf16(aH, bL, acc, 0, 0, 0);
      acc = __builtin_amdgcn_mfma_f32_32x32x16_bf16(aL, bH, acc, 0, 0, 0);
    }
  }

  #pragma unroll
  for (int i = 0; i < 16; ++i) {
    const int cr = (i & 3) + 8 * (i >> 2) + 4 * hh;
    out[(size_t)(m0 + mi + cr) * 1024 + n0 + ni + ln] = acc[i] + bcv;
  }
}

// ---------------------------------------------------------------------------
extern "C" void kernel_launch(void* const* d_in, const int* in_sizes, int n_in,
                              void* d_out, int out_size, void* d_ws, size_t ws_size,
                              hipStream_t stream) {
  const float* s_z    = (const float*)d_in[0];
  const float* s_s_in = (const float*)d_in[1];
  const float* pmask  = (const float*)d_in[2];
  const float* ln_g   = (const float*)d_in[3];
  const float* ln_b   = (const float*)d_in[4];
  const float* w1     = (const float*)d_in[5];
  const float* b1     = (const float*)d_in[6];
  const float* w2     = (const float*)d_in[7];
  const float* b2     = (const float*)d_in[8];
  const float* wc     = (const float*)d_in[9];
  const float* bc     = (const float*)d_in[10];
  float* outp = (float*)d_out;

  // ws layout: g[1024*128] gr[1024*128] Mc[1024] Mr[1024] (fp32, zeroed)
  //            then Ah/Al/Bh/Bl (bf16-as-short, 1024x1280 each)
  float* g  = (float*)d_ws;
  float* gr = g  + 1024 * 128;
  float* Mc = gr + 1024 * 128;
  float* Mr = Mc + 1024;
  short* Ah = (short*)(Mr + 1024);
  short* Al = Ah + (size_t)1024 * 1280;
  short* Bh = Al + (size_t)1024 * 1280;
  short* Bl = Bh + (size_t)1024 * 1280;

  hipMemsetAsync(d_ws, 0, (size_t)(2 * 1024 * 128 + 2048) * sizeof(float), stream);

  k_split<<<1280, 256, 0, stream>>>(s_s_in, wc, Ah, Al, Bh, Bl);
  k_pair<<<dim3(32, 32), 256, 0, stream>>>(s_z, pmask, ln_g, ln_b, w1, b1, g, gr, Mc, Mr);
  k_seqproj<<<32, 256, 0, stream>>>(g, w2, b2, Mc, Mr, Ah, Al);
  k_final<<<dim3(16, 16), 256, 0, stream>>>(Ah, Al, Bh, Bl, bc, outp);
}